// Round 10
// baseline (432.830 us; speedup 1.0000x reference)
//
#include <hip/hip_runtime.h>
#include <hip/hip_bf16.h>

#define ALPHA_ 0.2f
#define EPS_ 1e-12f

typedef short short8 __attribute__((ext_vector_type(8)));
typedef unsigned short ushort4v __attribute__((ext_vector_type(4)));
typedef float f32x4 __attribute__((ext_vector_type(4)));

constexpr int BB = 16, KK = 16, DD = 256, NNEG = 16384;
constexpr int ITERS = 5;   // Newton-Schulz iterations (odd; start at XA => final lands in XB)

// ---- workspace layout (float offsets) ---- total 5,309,440 floats (proven size)
constexpr size_t OFF_NL    = 0;         // 2M floats: neg-lo (overlays XA after Newton)
constexpr size_t OFF_XA_H  = 1048576;   // ping (X0 here)
constexpr size_t OFF_XA_L  = 1572864;
constexpr size_t OFF_XB_H  = 2097152;   // pong; FINAL A hi (never overlaid)
constexpr size_t OFF_XB_L  = 2621440;
constexpr size_t OFF_NH    = 3145728;   // 2M floats: neg-hi (overlays T+S after Newton)
constexpr size_t OFF_T_H   = 3145728;
constexpr size_t OFF_CS    = 3145728;   // colsum[16][256] (inside T region, consumed pre-Newton)
constexpr size_t OFF_C01   = 3149824;   // c0[16], c1[16]
constexpr size_t OFF_T_L   = 3670016;
constexpr size_t OFF_S_H   = 4194304;
constexpr size_t OFF_S_L   = 4718592;
constexpr size_t OFF_PA_H  = 5242880;   // 65536 ushorts
constexpr size_t OFF_PA_L  = 5275648;
constexpr size_t OFF_PAP   = 5308416;
constexpr size_t OFF_DPOS2 = 5308672;
constexpr size_t OFF_MINA  = 5308928;
constexpr size_t OFF_MINV  = 5309184;

// ---------- bf16 split helpers (RNE) ----------
__device__ inline unsigned short bf_hi(float x) {
    unsigned u = __float_as_uint(x);
    return (unsigned short)((u + 0x7fffu + ((u >> 16) & 1u)) >> 16);
}
__device__ inline float bf_tof(unsigned short h) { return __uint_as_float(((unsigned)h) << 16); }
__device__ inline void split2(float x, unsigned short& h, unsigned short& l) {
    h = bf_hi(x); l = bf_hi(x - bf_tof(h));
}

// ---------- prep 1: column abs-sums (Gershgorin), 256 blocks ----------
__global__ __launch_bounds__(256) void kcolsum(const float* __restrict__ Sig, float* __restrict__ cs) {
    int b = blockIdx.x >> 4, cg = blockIdx.x & 15;
    int t = threadIdx.x, tx = t & 15, rg = t >> 4;
    const float* S = Sig + (size_t)b * 65536;
    int col = cg * 16 + tx;
    float s = 0.f;
    #pragma unroll 4
    for (int i = rg * 16; i < rg * 16 + 16; ++i) s += fabsf(S[(size_t)i * 256 + col]);
    __shared__ float red[256];
    red[rg * 16 + tx] = s; __syncthreads();
    if (rg == 0) {
        float tot = 0.f;
        #pragma unroll
        for (int y = 0; y < 16; ++y) tot += red[y * 16 + tx];
        cs[b * 256 + col] = tot;
    }
}

// ---------- prep 2: G = max colsum -> degree-2 init coefficients ----------
__global__ __launch_bounds__(256) void kcoef(const float* __restrict__ cs, float* __restrict__ c01) {
    int t = threadIdx.x, b = t >> 4, ch = t & 15;
    float m = 0.f;
    #pragma unroll
    for (int i = 0; i < 16; ++i) m = fmaxf(m, cs[b * 256 + ch * 16 + i]);
    __shared__ float red[256];
    red[t] = m; __syncthreads();
    if (ch == 0) {
        float G = red[b * 16];
        #pragma unroll
        for (int y = 1; y < 16; ++y) G = fmaxf(G, red[b * 16 + y]);
        float c1 = -2.f / (G + (G + 1.f) * (G + 1.f) * 0.25f);
        c01[b] = -c1 * (G + 1.f); c01[16 + b] = c1;
    }
}

// ---------- prep 3: split S; X0 = c0*I + c1*S -> XA (split) ----------
__global__ __launch_bounds__(256) void kinit(const float* __restrict__ Sig, float* __restrict__ ws,
                                             const float* __restrict__ c01) {
    int idx = blockIdx.x * 256 + threadIdx.x;
    int b = idx >> 16, rc = idx & 65535;
    int r = rc >> 8, c = rc & 255;
    float v = Sig[idx];
    unsigned short h, l;
    split2(v, h, l);
    ((unsigned short*)(ws + OFF_S_H))[idx] = h; ((unsigned short*)(ws + OFF_S_L))[idx] = l;
    float x0 = c01[16 + b] * v + ((r == c) ? c01[b] : 0.f);
    split2(x0, h, l);
    ((unsigned short*)(ws + OFF_XA_H))[idx] = h; ((unsigned short*)(ws + OFF_XA_L))[idx] = l;
}

// ---------- batched 256x256 MFMA split GEMM, 32x32 tiles, 1024 blocks (4/CU) ----------
__global__ __launch_bounds__(256) void gemm_mfma(const unsigned short* __restrict__ Ah,
                                                 const unsigned short* __restrict__ Al,
                                                 const unsigned short* __restrict__ Bh,
                                                 const unsigned short* __restrict__ Bl,
                                                 unsigned short* __restrict__ Ch,
                                                 unsigned short* __restrict__ Cl, int mode2i) {
    int lin = blockIdx.x;
    int x = lin & 7, q = lin >> 3;                  // XCD x owns b in {2x, 2x+1}
    int b = x * 2 + (q >> 6);
    int tile = q & 63;
    int i0 = (tile >> 3) * 32, j0 = (tile & 7) * 32;
    size_t base = (size_t)b * 65536;
    int t = threadIdx.x, lane = t & 63, w = t >> 6;
    int wi = w & 1, wj = w >> 1;
    int l15 = lane & 15, lg = lane >> 4;
    f32x4 acc = {};
    int ar = i0 + wi * 16 + l15;
    int br = j0 + wj * 16 + l15;
    #pragma unroll
    for (int e0 = 0; e0 < 256; e0 += 32) {
        int eo = e0 + 8 * lg;
        size_t aoff = base + (size_t)ar * 256 + eo;
        size_t boff = base + (size_t)br * 256 + eo;     // symmetric: row == col
        short8 a_h = *reinterpret_cast<const short8*>(Ah + aoff);
        short8 a_l = *reinterpret_cast<const short8*>(Al + aoff);
        short8 b_h = *reinterpret_cast<const short8*>(Bh + boff);
        short8 b_l = *reinterpret_cast<const short8*>(Bl + boff);
        acc = __builtin_amdgcn_mfma_f32_16x16x32_bf16(a_h, b_h, acc, 0, 0, 0);
        acc = __builtin_amdgcn_mfma_f32_16x16x32_bf16(a_h, b_l, acc, 0, 0, 0);
        acc = __builtin_amdgcn_mfma_f32_16x16x32_bf16(a_l, b_h, acc, 0, 0, 0);
    }
    #pragma unroll
    for (int r = 0; r < 4; ++r) {
        int row = i0 + wi * 16 + 4 * lg + r;
        int col = j0 + wj * 16 + l15;
        float v = acc[r];
        if (mode2i) v = ((row == col) ? 2.f : 0.f) - v;
        unsigned short h, l; split2(v, h, l);
        size_t off = base + (size_t)row * 256 + col;
        Ch[off] = h; Cl[off] = l;
    }
}

// ---------- negatives pre-split (once) + min-buffer init ----------
__global__ __launch_bounds__(256) void knegsplit(const float* __restrict__ negs,
                                                 unsigned short* __restrict__ NH,
                                                 unsigned short* __restrict__ NL,
                                                 unsigned* __restrict__ mina,
                                                 unsigned* __restrict__ minv) {
    size_t i8 = ((size_t)blockIdx.x * 256 + threadIdx.x) * 8;
    f32x4 v0 = *reinterpret_cast<const f32x4*>(negs + i8);
    f32x4 v1 = *reinterpret_cast<const f32x4*>(negs + i8 + 4);
    short8 h, l;
    #pragma unroll
    for (int j = 0; j < 4; ++j) {
        unsigned short hh, ll;
        split2(v0[j], hh, ll); h[j] = (short)hh; l[j] = (short)ll;
        split2(v1[j], hh, ll); h[4 + j] = (short)hh; l[4 + j] = (short)ll;
    }
    *reinterpret_cast<short8*>(NH + i8) = h;
    *reinterpret_cast<short8*>(NL + i8) = l;
    if (blockIdx.x == 0) {
        mina[threadIdx.x] = 0x7f800000u; minv[threadIdx.x] = 0x7f800000u;
    }
}

// ---------- per (b,k): PA row (split), pAp, dpos2 ----------
__global__ __launch_bounds__(256) void k2(const float* __restrict__ Z1, const float* __restrict__ Z2,
                                          const int* __restrict__ match,
                                          const unsigned short* __restrict__ AH,
                                          const unsigned short* __restrict__ AL,
                                          float* __restrict__ ws) {
    int bk = blockIdx.x; int b = bk >> 4; int t = threadIdx.x;
    const unsigned short* Ah = AH + (size_t)b * 65536;
    const unsigned short* Al = AL + (size_t)b * 65536;
    __shared__ float z[DD], df[DD];
    __shared__ float red[256];
    int m = match[bk];
    float zv = Z1[(size_t)bk * DD + t];
    float qv = Z2[((size_t)b * KK + m) * DD + t];
    z[t] = zv; df[t] = zv - qv;
    __syncthreads();
    float pa = 0.f, da = 0.f;
    for (int e = 0; e < DD; ++e) {
        float Ae = bf_tof(Ah[(size_t)e * 256 + t]) + bf_tof(Al[(size_t)e * 256 + t]);
        pa = fmaf(z[e], Ae, pa);
        da = fmaf(df[e], Ae, da);
    }
    unsigned short ph, pl; split2(pa, ph, pl);
    ((unsigned short*)(ws + OFF_PA_H))[(size_t)bk * 256 + t] = ph;
    ((unsigned short*)(ws + OFF_PA_L))[(size_t)bk * 256 + t] = pl;
    float dfv = df[t];
    red[t] = pa * zv; __syncthreads();
    for (int s = 128; s > 0; s >>= 1) { if (t < s) red[t] += red[t + s]; __syncthreads(); }
    float pAp = red[0]; __syncthreads();
    red[t] = da * dfv; __syncthreads();
    for (int s = 128; s > 0; s >>= 1) { if (t < s) red[t] += red[t + s]; __syncthreads(); }
    if (t == 0) {
        ws[OFF_PAP + bk]   = pAp;
        ws[OFF_DPOS2 + bk] = fmaxf(red[0], EPS_);
    }
}

// ---------- main kernel: 8 waves x (2 f-tiles x 4 j), lean regs, (512,4) cap ----------
// Wave w: f-tiles {2w, 2w+1}; PA (16 rows) j-split: wave w<4 does PA x (j=w).
// acc 32+4 AGPR; staging 1 short8/thread (t<256: hi, t>=256: lo). Target <=128 regs.
__global__ __launch_bounds__(512, 4) void k3(const unsigned short* __restrict__ Ahi,
                                             const unsigned short* __restrict__ Alo,
                                             const unsigned short* __restrict__ PAh,
                                             const unsigned short* __restrict__ PAl,
                                             const unsigned short* __restrict__ NH,
                                             const unsigned short* __restrict__ NL,
                                             const float* __restrict__ pap,
                                             const float* __restrict__ dpos2,
                                             unsigned* __restrict__ mina,
                                             unsigned* __restrict__ minv) {
    __shared__ float smem[5120];                       // 20.5 KB: 4 buffers [64][40] ushort
    unsigned short* BH0 = (unsigned short*)smem;
    unsigned short* BL0 = BH0 + 2560;
    unsigned short* BH1 = BL0 + 2560;
    unsigned short* BL1 = BH1 + 2560;

    int lin = blockIdx.x;
    int x  = lin & 7;
    int q  = lin >> 3;
    int b  = q >> 5;
    int n0 = (x * 32 + (q & 31)) * 64;                 // XCD-local 2048-n slice
    int t = threadIdx.x, lane = t & 63, w = t >> 6;
    int l15 = lane & 15, lg = lane >> 4;
    const unsigned short* Ab  = Ahi + (size_t)b * 65536;
    const unsigned short* Al_ = Alo + (size_t)b * 65536;
    const unsigned short* Nh  = NH + (size_t)n0 * 256;
    const unsigned short* Nl  = NL + (size_t)n0 * 256;

    // staging: 64 rows x 32 e; threads 0-255 hi, 256-511 lo; 1 short8 each
    int sid = t & 255;
    int srow = sid >> 2, sq = sid & 3;
    bool hiSt = (t < 256);
    const unsigned short* sSrc = (hiSt ? Nh : Nl) + (size_t)srow * 256 + sq * 8;
    int soff = srow * 40 + sq * 8;
    unsigned short* sD0 = (hiSt ? BH0 : BL0) + soff;
    unsigned short* sD1 = (hiSt ? BH1 : BL1) + soff;

    const unsigned short* aBh = Ab  + (size_t)(w * 32 + l15) * 256 + 8 * lg;  // f-tiles 2w,2w+1
    const unsigned short* aBl = Al_ + (size_t)(w * 32 + l15) * 256 + 8 * lg;
    const unsigned short* pph = PAh + (size_t)b * 4096 + (size_t)l15 * 256 + 8 * lg;
    const unsigned short* ppl = PAl + (size_t)b * 4096 + (size_t)l15 * 256 + 8 * lg;

    f32x4 acc0[4] = {}, acc1[4] = {};
    f32x4 accp = {};

    // prologue: stage chunk 0 into buf0
    short8 sv = *reinterpret_cast<const short8*>(sSrc);
    *reinterpret_cast<short8*>(sD0) = sv;
    __syncthreads();

    #pragma unroll
    for (int c = 0; c < 8; ++c) {
        const unsigned short* cH = (c & 1) ? BH1 : BH0;
        const unsigned short* cL = (c & 1) ? BL1 : BL0;
        if (c < 7)                                      // early-issue next-chunk staging load
            sv = *reinterpret_cast<const short8*>(sSrc + (c + 1) * 32);
        short8 ah0 = *reinterpret_cast<const short8*>(aBh + c * 32);
        short8 al0 = *reinterpret_cast<const short8*>(aBl + c * 32);
        short8 ah1 = *reinterpret_cast<const short8*>(aBh + 16 * 256 + c * 32);
        short8 al1 = *reinterpret_cast<const short8*>(aBl + 16 * 256 + c * 32);
        short8 ph_ = {}, pl_ = {};
        if (w < 4) {
            ph_ = *reinterpret_cast<const short8*>(pph + c * 32);
            pl_ = *reinterpret_cast<const short8*>(ppl + c * 32);
        }
        #pragma unroll
        for (int j = 0; j < 4; ++j) {                   // j-outer: LDS read once per j
            short8 bh = *reinterpret_cast<const short8*>(cH + (j * 16 + l15) * 40 + 8 * lg);
            short8 bl = *reinterpret_cast<const short8*>(cL + (j * 16 + l15) * 40 + 8 * lg);
            acc0[j] = __builtin_amdgcn_mfma_f32_16x16x32_bf16(ah0, bh, acc0[j], 0, 0, 0);
            acc0[j] = __builtin_amdgcn_mfma_f32_16x16x32_bf16(ah0, bl, acc0[j], 0, 0, 0);
            acc0[j] = __builtin_amdgcn_mfma_f32_16x16x32_bf16(al0, bh, acc0[j], 0, 0, 0);
            acc1[j] = __builtin_amdgcn_mfma_f32_16x16x32_bf16(ah1, bh, acc1[j], 0, 0, 0);
            acc1[j] = __builtin_amdgcn_mfma_f32_16x16x32_bf16(ah1, bl, acc1[j], 0, 0, 0);
            acc1[j] = __builtin_amdgcn_mfma_f32_16x16x32_bf16(al1, bh, acc1[j], 0, 0, 0);
            if (w == j) {                               // w<4 implied (j<4)
                accp = __builtin_amdgcn_mfma_f32_16x16x32_bf16(ph_, bh, accp, 0, 0, 0);
                accp = __builtin_amdgcn_mfma_f32_16x16x32_bf16(ph_, bl, accp, 0, 0, 0);
                accp = __builtin_amdgcn_mfma_f32_16x16x32_bf16(pl_, bh, accp, 0, 0, 0);
            }
        }
        if (c < 7)                                      // write NEXT buffer (distinct from cur)
            *reinterpret_cast<short8*>((c & 1) ? sD0 : sD1) = sv;
        __syncthreads();
    }

    // ---- epilogue (smem reused after final barrier) ----
    float* pAn_l = smem;            // [64][17] = 1088
    float* nAnp  = smem + 1088;     // [8][64]
    float* nAn_l = smem + 1600;     // [64]
    float* reda  = smem + 1664;     // [256]
    float* redv  = smem + 1920;     // [256]

    if (w < 4) {                                        // pAn for n = w*16+l15, k = 4lg+r
        #pragma unroll
        for (int r = 0; r < 4; ++r)
            pAn_l[(w * 16 + l15) * 17 + 4 * lg + r] = accp[r];
    }
    #pragma unroll
    for (int j = 0; j < 4; ++j) {
        int n = j * 16 + l15;
        float p = 0.f;
        {
            int fb0 = w * 32 + 4 * lg;
            ushort4v wh0 = *reinterpret_cast<const ushort4v*>(NH + (size_t)(n0 + n) * 256 + fb0);
            ushort4v wl0 = *reinterpret_cast<const ushort4v*>(NL + (size_t)(n0 + n) * 256 + fb0);
            ushort4v wh1 = *reinterpret_cast<const ushort4v*>(NH + (size_t)(n0 + n) * 256 + fb0 + 16);
            ushort4v wl1 = *reinterpret_cast<const ushort4v*>(NL + (size_t)(n0 + n) * 256 + fb0 + 16);
            #pragma unroll
            for (int r = 0; r < 4; ++r) {
                p = fmaf(acc0[j][r], bf_tof(wh0[r]) + bf_tof(wl0[r]), p);
                p = fmaf(acc1[j][r], bf_tof(wh1[r]) + bf_tof(wl1[r]), p);
            }
        }
        p += __shfl_xor(p, 16);                         // reduce over lg
        p += __shfl_xor(p, 32);
        if (lane < 16) nAnp[w * 64 + n] = p;
    }
    __syncthreads();
    if (t < 64) {
        float s = 0.f;
        #pragma unroll
        for (int ww = 0; ww < 8; ++ww) s += nAnp[ww * 64 + t];
        nAn_l[t] = s;
    }
    __syncthreads();
    if (t < 256) {
        int tx = t & 15, ty = t >> 4;                   // ty 0..15, 4 n each
        float pApk = pap[b * 16 + tx];
        float dp2  = dpos2[b * 16 + tx];
        float mn_a = __uint_as_float(0x7f800000u), mn_v = mn_a;
        #pragma unroll
        for (int ii = 0; ii < 4; ++ii) {
            int n = ty * 4 + ii;
            float d2v = pApk - 2.f * pAn_l[n * 17 + tx] + nAn_l[n];
            float cc = fmaxf(d2v, EPS_);
            mn_a = fminf(mn_a, cc);
            if (cc > dp2) mn_v = fminf(mn_v, cc);
        }
        reda[ty * 16 + tx] = mn_a; redv[ty * 16 + tx] = mn_v;
    }
    __syncthreads();
    if (t < 16) {
        float ra = reda[t], rv = redv[t];
        #pragma unroll
        for (int y = 1; y < 16; ++y) {
            ra = fminf(ra, reda[y * 16 + t]);
            rv = fminf(rv, redv[y * 16 + t]);
        }
        atomicMin(&mina[b * 16 + t], __float_as_uint(ra));
        atomicMin(&minv[b * 16 + t], __float_as_uint(rv));
    }
}

// ---------- final loss ----------
__global__ __launch_bounds__(256) void k5(const float* __restrict__ dpos2,
                                          const unsigned* __restrict__ mina,
                                          const unsigned* __restrict__ minv,
                                          float* __restrict__ out) {
    int t = threadIdx.x;
    __shared__ float red[256];
    float dp = sqrtf(dpos2[t]);
    unsigned mv = minv[t], ma = mina[t];
    unsigned sel = (mv < 0x7f800000u) ? mv : ma;
    float dn = sqrtf(__uint_as_float(sel));
    red[t] = fmaxf(dp - dn + ALPHA_, 0.f);
    __syncthreads();
    for (int s = 128; s > 0; s >>= 1) { if (t < s) red[t] += red[t + s]; __syncthreads(); }
    if (t == 0) out[0] = red[0] * (1.f / 256.f);
}

extern "C" void kernel_launch(void* const* d_in, const int* in_sizes, int n_in,
                              void* d_out, int out_size, void* d_ws, size_t ws_size,
                              hipStream_t stream) {
    (void)in_sizes; (void)n_in; (void)out_size; (void)ws_size;
    const float* Z1   = (const float*)d_in[0];
    const float* Z2   = (const float*)d_in[1];
    const int*   mat  = (const int*)d_in[2];
    const float* negs = (const float*)d_in[3];
    const float* Sig  = (const float*)d_in[4];
    float* ws = (float*)d_ws;
    unsigned short* S_H  = (unsigned short*)(ws + OFF_S_H);
    unsigned short* S_L  = (unsigned short*)(ws + OFF_S_L);
    unsigned short* XA_H = (unsigned short*)(ws + OFF_XA_H);
    unsigned short* XA_L = (unsigned short*)(ws + OFF_XA_L);
    unsigned short* XB_H = (unsigned short*)(ws + OFF_XB_H);
    unsigned short* XB_L = (unsigned short*)(ws + OFF_XB_L);
    unsigned short* T_H  = (unsigned short*)(ws + OFF_T_H);
    unsigned short* T_L  = (unsigned short*)(ws + OFF_T_L);
    unsigned short* PA_H = (unsigned short*)(ws + OFF_PA_H);
    unsigned short* PA_L = (unsigned short*)(ws + OFF_PA_L);
    unsigned short* NH   = (unsigned short*)(ws + OFF_NH);
    unsigned short* NL   = (unsigned short*)(ws + OFF_NL);
    unsigned* mina = (unsigned*)(ws + OFF_MINA);
    unsigned* minv = (unsigned*)(ws + OFF_MINV);
    float* out = (float*)d_out;

    kcolsum<<<256, 256, 0, stream>>>(Sig, ws + OFF_CS);
    kcoef<<<1, 256, 0, stream>>>(ws + OFF_CS, ws + OFF_C01);
    kinit<<<4096, 256, 0, stream>>>(Sig, ws, ws + OFF_C01);

    unsigned short* pah = XA_H; unsigned short* pal = XA_L;   // start XA: odd ITERS => final XB
    unsigned short* pbh = XB_H; unsigned short* pbl = XB_L;
    for (int it = 0; it < ITERS; ++it) {
        gemm_mfma<<<1024, 256, 0, stream>>>(S_H, S_L, pah, pal, T_H, T_L, 1);   // T = 2I - S@X
        gemm_mfma<<<1024, 256, 0, stream>>>(pah, pal, T_H, T_L, pbh, pbl, 0);   // X' = X@T
        unsigned short* th = pah; pah = pbh; pbh = th;
        unsigned short* tl = pal; pal = pbl; pbl = tl;
    }
    // ITERS=5 (odd) => final split inverse in XB (== pah/pal); XA/T/S now dead

    knegsplit<<<NNEG * DD / 8 / 256, 256, 0, stream>>>(negs, NH, NL, mina, minv);
    k2<<<BB * KK, 256, 0, stream>>>(Z1, Z2, mat, pah, pal, ws);
    k3<<<BB * NNEG / 64, 512, 0, stream>>>(pah, pal, PA_H, PA_L, NH, NL,
                                           ws + OFF_PAP, ws + OFF_DPOS2, mina, minv);
    k5<<<1, 256, 0, stream>>>(ws + OFF_DPOS2, mina, minv, out);
}

// Round 11
// 371.903 us; speedup vs baseline: 1.1638x; 1.1638x over previous
//
#include <hip/hip_runtime.h>
#include <hip/hip_bf16.h>

#define ALPHA_ 0.2f
#define EPS_ 1e-12f

typedef short short8 __attribute__((ext_vector_type(8)));
typedef unsigned short ushort4v __attribute__((ext_vector_type(4)));
typedef float f32x4 __attribute__((ext_vector_type(4)));

constexpr int BB = 16, KK = 16, DD = 256, NNEG = 16384;
constexpr int ITERS = 5;   // Newton-Schulz iterations (odd; start at XA => final lands in XB)

// ---- workspace layout (float offsets) ---- total 5,309,440 floats (proven size)
constexpr size_t OFF_NL    = 0;         // 2M floats: neg-lo (overlays XA after Newton)
constexpr size_t OFF_XA_H  = 1048576;   // ping (X0 here)
constexpr size_t OFF_XA_L  = 1572864;
constexpr size_t OFF_XB_H  = 2097152;   // pong; FINAL A hi (never overlaid)
constexpr size_t OFF_XB_L  = 2621440;
constexpr size_t OFF_NH    = 3145728;   // 2M floats: neg-hi (overlays T+S after Newton)
constexpr size_t OFF_T_H   = 3145728;
constexpr size_t OFF_CS    = 3145728;   // colsum[16][256] (inside T region, consumed pre-Newton)
constexpr size_t OFF_C01   = 3149824;   // c0[16], c1[16]
constexpr size_t OFF_T_L   = 3670016;
constexpr size_t OFF_S_H   = 4194304;
constexpr size_t OFF_S_L   = 4718592;
constexpr size_t OFF_PA_H  = 5242880;   // 65536 ushorts
constexpr size_t OFF_PA_L  = 5275648;
constexpr size_t OFF_PAP   = 5308416;
constexpr size_t OFF_DPOS2 = 5308672;
constexpr size_t OFF_MINA  = 5308928;
constexpr size_t OFF_MINV  = 5309184;

// ---------- bf16 split helpers (RNE) ----------
__device__ inline unsigned short bf_hi(float x) {
    unsigned u = __float_as_uint(x);
    return (unsigned short)((u + 0x7fffu + ((u >> 16) & 1u)) >> 16);
}
__device__ inline float bf_tof(unsigned short h) { return __uint_as_float(((unsigned)h) << 16); }
__device__ inline void split2(float x, unsigned short& h, unsigned short& l) {
    h = bf_hi(x); l = bf_hi(x - bf_tof(h));
}

// ---------- prep 1: column abs-sums (Gershgorin), 256 blocks ----------
__global__ __launch_bounds__(256) void kcolsum(const float* __restrict__ Sig, float* __restrict__ cs) {
    int b = blockIdx.x >> 4, cg = blockIdx.x & 15;
    int t = threadIdx.x, tx = t & 15, rg = t >> 4;
    const float* S = Sig + (size_t)b * 65536;
    int col = cg * 16 + tx;
    float s = 0.f;
    #pragma unroll 4
    for (int i = rg * 16; i < rg * 16 + 16; ++i) s += fabsf(S[(size_t)i * 256 + col]);
    __shared__ float red[256];
    red[rg * 16 + tx] = s; __syncthreads();
    if (rg == 0) {
        float tot = 0.f;
        #pragma unroll
        for (int y = 0; y < 16; ++y) tot += red[y * 16 + tx];
        cs[b * 256 + col] = tot;
    }
}

// ---------- prep 2: G = max colsum -> degree-2 init coefficients ----------
__global__ __launch_bounds__(256) void kcoef(const float* __restrict__ cs, float* __restrict__ c01) {
    int t = threadIdx.x, b = t >> 4, ch = t & 15;
    float m = 0.f;
    #pragma unroll
    for (int i = 0; i < 16; ++i) m = fmaxf(m, cs[b * 256 + ch * 16 + i]);
    __shared__ float red[256];
    red[t] = m; __syncthreads();
    if (ch == 0) {
        float G = red[b * 16];
        #pragma unroll
        for (int y = 1; y < 16; ++y) G = fmaxf(G, red[b * 16 + y]);
        float c1 = -2.f / (G + (G + 1.f) * (G + 1.f) * 0.25f);
        c01[b] = -c1 * (G + 1.f); c01[16 + b] = c1;
    }
}

// ---------- prep 3: split S; X0 = c0*I + c1*S -> XA (split) ----------
__global__ __launch_bounds__(256) void kinit(const float* __restrict__ Sig, float* __restrict__ ws,
                                             const float* __restrict__ c01) {
    int idx = blockIdx.x * 256 + threadIdx.x;
    int b = idx >> 16, rc = idx & 65535;
    int r = rc >> 8, c = rc & 255;
    float v = Sig[idx];
    unsigned short h, l;
    split2(v, h, l);
    ((unsigned short*)(ws + OFF_S_H))[idx] = h; ((unsigned short*)(ws + OFF_S_L))[idx] = l;
    float x0 = c01[16 + b] * v + ((r == c) ? c01[b] : 0.f);
    split2(x0, h, l);
    ((unsigned short*)(ws + OFF_XA_H))[idx] = h; ((unsigned short*)(ws + OFF_XA_L))[idx] = l;
}

// ---------- batched 256x256 MFMA split GEMM, 32x32 tiles, 1024 blocks (4/CU) ----------
// v2: DUAL accumulators (even/odd e-chunks) -> dependent-MFMA chain 24 -> 12.
__global__ __launch_bounds__(256) void gemm_mfma(const unsigned short* __restrict__ Ah,
                                                 const unsigned short* __restrict__ Al,
                                                 const unsigned short* __restrict__ Bh,
                                                 const unsigned short* __restrict__ Bl,
                                                 unsigned short* __restrict__ Ch,
                                                 unsigned short* __restrict__ Cl, int mode2i) {
    int lin = blockIdx.x;
    int x = lin & 7, q = lin >> 3;                  // XCD x owns b in {2x, 2x+1}
    int b = x * 2 + (q >> 6);
    int tile = q & 63;
    int i0 = (tile >> 3) * 32, j0 = (tile & 7) * 32;
    size_t base = (size_t)b * 65536;
    int t = threadIdx.x, lane = t & 63, w = t >> 6;
    int wi = w & 1, wj = w >> 1;
    int l15 = lane & 15, lg = lane >> 4;
    f32x4 acc0 = {}, acc1 = {};
    int ar = i0 + wi * 16 + l15;
    int br = j0 + wj * 16 + l15;
    #pragma unroll
    for (int e0 = 0; e0 < 256; e0 += 64) {
        int eo = e0 + 8 * lg;
        size_t aoff = base + (size_t)ar * 256 + eo;
        size_t boff = base + (size_t)br * 256 + eo;     // symmetric: row == col
        short8 a_h0 = *reinterpret_cast<const short8*>(Ah + aoff);
        short8 a_l0 = *reinterpret_cast<const short8*>(Al + aoff);
        short8 b_h0 = *reinterpret_cast<const short8*>(Bh + boff);
        short8 b_l0 = *reinterpret_cast<const short8*>(Bl + boff);
        short8 a_h1 = *reinterpret_cast<const short8*>(Ah + aoff + 32);
        short8 a_l1 = *reinterpret_cast<const short8*>(Al + aoff + 32);
        short8 b_h1 = *reinterpret_cast<const short8*>(Bh + boff + 32);
        short8 b_l1 = *reinterpret_cast<const short8*>(Bl + boff + 32);
        acc0 = __builtin_amdgcn_mfma_f32_16x16x32_bf16(a_h0, b_h0, acc0, 0, 0, 0);
        acc1 = __builtin_amdgcn_mfma_f32_16x16x32_bf16(a_h1, b_h1, acc1, 0, 0, 0);
        acc0 = __builtin_amdgcn_mfma_f32_16x16x32_bf16(a_h0, b_l0, acc0, 0, 0, 0);
        acc1 = __builtin_amdgcn_mfma_f32_16x16x32_bf16(a_h1, b_l1, acc1, 0, 0, 0);
        acc0 = __builtin_amdgcn_mfma_f32_16x16x32_bf16(a_l0, b_h0, acc0, 0, 0, 0);
        acc1 = __builtin_amdgcn_mfma_f32_16x16x32_bf16(a_l1, b_h1, acc1, 0, 0, 0);
    }
    #pragma unroll
    for (int r = 0; r < 4; ++r) {
        int row = i0 + wi * 16 + 4 * lg + r;
        int col = j0 + wj * 16 + l15;
        float v = acc0[r] + acc1[r];
        if (mode2i) v = ((row == col) ? 2.f : 0.f) - v;
        unsigned short h, l; split2(v, h, l);
        size_t off = base + (size_t)row * 256 + col;
        Ch[off] = h; Cl[off] = l;
    }
}

// ---------- negatives pre-split (once) + min-buffer init ----------
__global__ __launch_bounds__(256) void knegsplit(const float* __restrict__ negs,
                                                 unsigned short* __restrict__ NH,
                                                 unsigned short* __restrict__ NL,
                                                 unsigned* __restrict__ mina,
                                                 unsigned* __restrict__ minv) {
    size_t i8 = ((size_t)blockIdx.x * 256 + threadIdx.x) * 8;
    f32x4 v0 = *reinterpret_cast<const f32x4*>(negs + i8);
    f32x4 v1 = *reinterpret_cast<const f32x4*>(negs + i8 + 4);
    short8 h, l;
    #pragma unroll
    for (int j = 0; j < 4; ++j) {
        unsigned short hh, ll;
        split2(v0[j], hh, ll); h[j] = (short)hh; l[j] = (short)ll;
        split2(v1[j], hh, ll); h[4 + j] = (short)hh; l[4 + j] = (short)ll;
    }
    *reinterpret_cast<short8*>(NH + i8) = h;
    *reinterpret_cast<short8*>(NL + i8) = l;
    if (blockIdx.x == 0) {
        mina[threadIdx.x] = 0x7f800000u; minv[threadIdx.x] = 0x7f800000u;
    }
}

// ---------- per (b,k): PA row (split), pAp, dpos2 ----------
__global__ __launch_bounds__(256) void k2(const float* __restrict__ Z1, const float* __restrict__ Z2,
                                          const int* __restrict__ match,
                                          const unsigned short* __restrict__ AH,
                                          const unsigned short* __restrict__ AL,
                                          float* __restrict__ ws) {
    int bk = blockIdx.x; int b = bk >> 4; int t = threadIdx.x;
    const unsigned short* Ah = AH + (size_t)b * 65536;
    const unsigned short* Al = AL + (size_t)b * 65536;
    __shared__ float z[DD], df[DD];
    __shared__ float red[256];
    int m = match[bk];
    float zv = Z1[(size_t)bk * DD + t];
    float qv = Z2[((size_t)b * KK + m) * DD + t];
    z[t] = zv; df[t] = zv - qv;
    __syncthreads();
    float pa = 0.f, da = 0.f;
    for (int e = 0; e < DD; ++e) {
        float Ae = bf_tof(Ah[(size_t)e * 256 + t]) + bf_tof(Al[(size_t)e * 256 + t]);
        pa = fmaf(z[e], Ae, pa);
        da = fmaf(df[e], Ae, da);
    }
    unsigned short ph, pl; split2(pa, ph, pl);
    ((unsigned short*)(ws + OFF_PA_H))[(size_t)bk * 256 + t] = ph;
    ((unsigned short*)(ws + OFF_PA_L))[(size_t)bk * 256 + t] = pl;
    float dfv = df[t];
    red[t] = pa * zv; __syncthreads();
    for (int s = 128; s > 0; s >>= 1) { if (t < s) red[t] += red[t + s]; __syncthreads(); }
    float pAp = red[0]; __syncthreads();
    red[t] = da * dfv; __syncthreads();
    for (int s = 128; s > 0; s >>= 1) { if (t < s) red[t] += red[t + s]; __syncthreads(); }
    if (t == 0) {
        ws[OFF_PAP + bk]   = pAp;
        ws[OFF_DPOS2 + bk] = fmaxf(red[0], EPS_);
    }
}

// ---------- main kernel: full-K LDS staging, ZERO barriers in compute loop ----------
// 512 thr = 8 waves. Stage entire 64-n x 256-e neg tile (hi+lo, 67.6 KB) once; one barrier;
// then free-running MFMA loop (waves drift, loads pipeline). Epilogue weights from LDS.
// Wave w: f-tiles {2w, 2w+1}; PA j-split: wave w<4 does PA x (j=w).
__global__ __launch_bounds__(512, 2) void k3(const unsigned short* __restrict__ Ahi,
                                             const unsigned short* __restrict__ Alo,
                                             const unsigned short* __restrict__ PAh,
                                             const unsigned short* __restrict__ PAl,
                                             const unsigned short* __restrict__ NH,
                                             const unsigned short* __restrict__ NL,
                                             const float* __restrict__ pap,
                                             const float* __restrict__ dpos2,
                                             unsigned* __restrict__ mina,
                                             unsigned* __restrict__ minv) {
    constexpr int LD = 264;                            // row pitch (ushorts): 528 B, 16B-aligned
    __shared__ unsigned short Bh[64 * LD];             // negatives hi  (33.8 KB)
    __shared__ unsigned short Bl[64 * LD];             // negatives lo  (33.8 KB)
    __shared__ float ep[2176];                         // epilogue buffers (8.7 KB)

    int lin = blockIdx.x;
    int x  = lin & 7;
    int q  = lin >> 3;
    int b  = q >> 5;
    int n0 = (x * 32 + (q & 31)) * 64;                 // XCD-local 2048-n slice
    int t = threadIdx.x, lane = t & 63, w = t >> 6;
    int l15 = lane & 15, lg = lane >> 4;
    const unsigned short* Ab  = Ahi + (size_t)b * 65536;
    const unsigned short* Al_ = Alo + (size_t)b * 65536;
    const unsigned short* Nh  = NH + (size_t)n0 * 256;
    const unsigned short* Nl  = NL + (size_t)n0 * 256;

    // ---- one-shot staging: thread t -> row t>>3, 32-ushort octant t&7 ----
    {
        int row = t >> 3, oct = t & 7;
        const unsigned short* gh = Nh + (size_t)row * 256 + oct * 32;
        const unsigned short* gl = Nl + (size_t)row * 256 + oct * 32;
        unsigned short* dh = Bh + row * LD + oct * 32;
        unsigned short* dl = Bl + row * LD + oct * 32;
        #pragma unroll
        for (int k = 0; k < 4; ++k) {
            *reinterpret_cast<short8*>(dh + k * 8) = *reinterpret_cast<const short8*>(gh + k * 8);
            *reinterpret_cast<short8*>(dl + k * 8) = *reinterpret_cast<const short8*>(gl + k * 8);
        }
    }
    __syncthreads();                                   // the ONLY pre-compute barrier

    const unsigned short* aBh = Ab  + (size_t)(w * 32 + l15) * 256 + 8 * lg;  // f-tiles 2w,2w+1
    const unsigned short* aBl = Al_ + (size_t)(w * 32 + l15) * 256 + 8 * lg;
    const unsigned short* pph = PAh + (size_t)b * 4096 + (size_t)l15 * 256 + 8 * lg;
    const unsigned short* ppl = PAl + (size_t)b * 4096 + (size_t)l15 * 256 + 8 * lg;

    f32x4 acc0[4] = {}, acc1[4] = {};
    f32x4 accp = {};

    #pragma unroll
    for (int c = 0; c < 8; ++c) {
        short8 ah0 = *reinterpret_cast<const short8*>(aBh + c * 32);
        short8 al0 = *reinterpret_cast<const short8*>(aBl + c * 32);
        short8 ah1 = *reinterpret_cast<const short8*>(aBh + 16 * 256 + c * 32);
        short8 al1 = *reinterpret_cast<const short8*>(aBl + 16 * 256 + c * 32);
        short8 ph_ = {}, pl_ = {};
        if (w < 4) {
            ph_ = *reinterpret_cast<const short8*>(pph + c * 32);
            pl_ = *reinterpret_cast<const short8*>(ppl + c * 32);
        }
        #pragma unroll
        for (int j = 0; j < 4; ++j) {
            short8 bh = *reinterpret_cast<const short8*>(Bh + (j * 16 + l15) * LD + c * 32 + 8 * lg);
            short8 bl = *reinterpret_cast<const short8*>(Bl + (j * 16 + l15) * LD + c * 32 + 8 * lg);
            acc0[j] = __builtin_amdgcn_mfma_f32_16x16x32_bf16(ah0, bh, acc0[j], 0, 0, 0);
            acc0[j] = __builtin_amdgcn_mfma_f32_16x16x32_bf16(ah0, bl, acc0[j], 0, 0, 0);
            acc0[j] = __builtin_amdgcn_mfma_f32_16x16x32_bf16(al0, bh, acc0[j], 0, 0, 0);
            acc1[j] = __builtin_amdgcn_mfma_f32_16x16x32_bf16(ah1, bh, acc1[j], 0, 0, 0);
            acc1[j] = __builtin_amdgcn_mfma_f32_16x16x32_bf16(ah1, bl, acc1[j], 0, 0, 0);
            acc1[j] = __builtin_amdgcn_mfma_f32_16x16x32_bf16(al1, bh, acc1[j], 0, 0, 0);
            if (w == j) {                              // w<4 implied (j<4)
                accp = __builtin_amdgcn_mfma_f32_16x16x32_bf16(ph_, bh, accp, 0, 0, 0);
                accp = __builtin_amdgcn_mfma_f32_16x16x32_bf16(ph_, bl, accp, 0, 0, 0);
                accp = __builtin_amdgcn_mfma_f32_16x16x32_bf16(pl_, bh, accp, 0, 0, 0);
            }
        }
    }

    // ---- epilogue: weights from LDS; cross-wave reduce in ep[] ----
    float* pAn_l = ep;              // [64][17] = 1088
    float* nAnp  = ep + 1088;       // [8][64]
    float* nAn_l = ep + 1600;       // [64]
    float* reda  = ep + 1664;       // [256]
    float* redv  = ep + 1920;       // [256]

    if (w < 4) {                                        // pAn for n = w*16+l15, k = 4lg+r
        #pragma unroll
        for (int r = 0; r < 4; ++r)
            pAn_l[(w * 16 + l15) * 17 + 4 * lg + r] = accp[r];
    }
    #pragma unroll
    for (int j = 0; j < 4; ++j) {
        int n = j * 16 + l15;
        float p = 0.f;
        {
            int fb0 = w * 32 + 4 * lg;
            ushort4v wh0 = *reinterpret_cast<const ushort4v*>(Bh + n * LD + fb0);
            ushort4v wl0 = *reinterpret_cast<const ushort4v*>(Bl + n * LD + fb0);
            ushort4v wh1 = *reinterpret_cast<const ushort4v*>(Bh + n * LD + fb0 + 16);
            ushort4v wl1 = *reinterpret_cast<const ushort4v*>(Bl + n * LD + fb0 + 16);
            #pragma unroll
            for (int r = 0; r < 4; ++r) {
                p = fmaf(acc0[j][r], bf_tof(wh0[r]) + bf_tof(wl0[r]), p);
                p = fmaf(acc1[j][r], bf_tof(wh1[r]) + bf_tof(wl1[r]), p);
            }
        }
        p += __shfl_xor(p, 16);                         // reduce over lg
        p += __shfl_xor(p, 32);
        if (lane < 16) nAnp[w * 64 + n] = p;
    }
    __syncthreads();
    if (t < 64) {
        float s = 0.f;
        #pragma unroll
        for (int ww = 0; ww < 8; ++ww) s += nAnp[ww * 64 + t];
        nAn_l[t] = s;
    }
    __syncthreads();
    if (t < 256) {
        int tx = t & 15, ty = t >> 4;                   // ty 0..15, 4 n each
        float pApk = pap[b * 16 + tx];
        float dp2  = dpos2[b * 16 + tx];
        float mn_a = __uint_as_float(0x7f800000u), mn_v = mn_a;
        #pragma unroll
        for (int ii = 0; ii < 4; ++ii) {
            int n = ty * 4 + ii;
            float d2v = pApk - 2.f * pAn_l[n * 17 + tx] + nAn_l[n];
            float cc = fmaxf(d2v, EPS_);
            mn_a = fminf(mn_a, cc);
            if (cc > dp2) mn_v = fminf(mn_v, cc);
        }
        reda[ty * 16 + tx] = mn_a; redv[ty * 16 + tx] = mn_v;
    }
    __syncthreads();
    if (t < 16) {
        float ra = reda[t], rv = redv[t];
        #pragma unroll
        for (int y = 1; y < 16; ++y) {
            ra = fminf(ra, reda[y * 16 + t]);
            rv = fminf(rv, redv[y * 16 + t]);
        }
        atomicMin(&mina[b * 16 + t], __float_as_uint(ra));
        atomicMin(&minv[b * 16 + t], __float_as_uint(rv));
    }
}

// ---------- final loss ----------
__global__ __launch_bounds__(256) void k5(const float* __restrict__ dpos2,
                                          const unsigned* __restrict__ mina,
                                          const unsigned* __restrict__ minv,
                                          float* __restrict__ out) {
    int t = threadIdx.x;
    __shared__ float red[256];
    float dp = sqrtf(dpos2[t]);
    unsigned mv = minv[t], ma = mina[t];
    unsigned sel = (mv < 0x7f800000u) ? mv : ma;
    float dn = sqrtf(__uint_as_float(sel));
    red[t] = fmaxf(dp - dn + ALPHA_, 0.f);
    __syncthreads();
    for (int s = 128; s > 0; s >>= 1) { if (t < s) red[t] += red[t + s]; __syncthreads(); }
    if (t == 0) out[0] = red[0] * (1.f / 256.f);
}

extern "C" void kernel_launch(void* const* d_in, const int* in_sizes, int n_in,
                              void* d_out, int out_size, void* d_ws, size_t ws_size,
                              hipStream_t stream) {
    (void)in_sizes; (void)n_in; (void)out_size; (void)ws_size;
    const float* Z1   = (const float*)d_in[0];
    const float* Z2   = (const float*)d_in[1];
    const int*   mat  = (const int*)d_in[2];
    const float* negs = (const float*)d_in[3];
    const float* Sig  = (const float*)d_in[4];
    float* ws = (float*)d_ws;
    unsigned short* S_H  = (unsigned short*)(ws + OFF_S_H);
    unsigned short* S_L  = (unsigned short*)(ws + OFF_S_L);
    unsigned short* XA_H = (unsigned short*)(ws + OFF_XA_H);
    unsigned short* XA_L = (unsigned short*)(ws + OFF_XA_L);
    unsigned short* XB_H = (unsigned short*)(ws + OFF_XB_H);
    unsigned short* XB_L = (unsigned short*)(ws + OFF_XB_L);
    unsigned short* T_H  = (unsigned short*)(ws + OFF_T_H);
    unsigned short* T_L  = (unsigned short*)(ws + OFF_T_L);
    unsigned short* PA_H = (unsigned short*)(ws + OFF_PA_H);
    unsigned short* PA_L = (unsigned short*)(ws + OFF_PA_L);
    unsigned short* NH   = (unsigned short*)(ws + OFF_NH);
    unsigned short* NL   = (unsigned short*)(ws + OFF_NL);
    unsigned* mina = (unsigned*)(ws + OFF_MINA);
    unsigned* minv = (unsigned*)(ws + OFF_MINV);
    float* out = (float*)d_out;

    kcolsum<<<256, 256, 0, stream>>>(Sig, ws + OFF_CS);
    kcoef<<<1, 256, 0, stream>>>(ws + OFF_CS, ws + OFF_C01);
    kinit<<<4096, 256, 0, stream>>>(Sig, ws, ws + OFF_C01);

    unsigned short* pah = XA_H; unsigned short* pal = XA_L;   // start XA: odd ITERS => final XB
    unsigned short* pbh = XB_H; unsigned short* pbl = XB_L;
    for (int it = 0; it < ITERS; ++it) {
        gemm_mfma<<<1024, 256, 0, stream>>>(S_H, S_L, pah, pal, T_H, T_L, 1);   // T = 2I - S@X
        gemm_mfma<<<1024, 256, 0, stream>>>(pah, pal, T_H, T_L, pbh, pbl, 0);   // X' = X@T
        unsigned short* th = pah; pah = pbh; pbh = th;
        unsigned short* tl = pal; pal = pbl; pbl = tl;
    }
    // ITERS=5 (odd) => final split inverse in XB (== pah/pal); XA/T/S now dead

    knegsplit<<<NNEG * DD / 8 / 256, 256, 0, stream>>>(negs, NH, NL, mina, minv);
    k2<<<BB * KK, 256, 0, stream>>>(Z1, Z2, mat, pah, pal, ws);
    k3<<<BB * NNEG / 64, 512, 0, stream>>>(pah, pal, PA_H, PA_L, NH, NL,
                                           ws + OFF_PAP, ws + OFF_DPOS2, mina, minv);
    k5<<<1, 256, 0, stream>>>(ws + OFF_DPOS2, mina, minv, out);
}

// Round 12
// 371.223 us; speedup vs baseline: 1.1660x; 1.0018x over previous
//
#include <hip/hip_runtime.h>
#include <hip/hip_bf16.h>

#define ALPHA_ 0.2f
#define EPS_ 1e-12f

typedef short short8 __attribute__((ext_vector_type(8)));
typedef unsigned short ushort4v __attribute__((ext_vector_type(4)));
typedef float f32x4 __attribute__((ext_vector_type(4)));

constexpr int BB = 16, KK = 16, DD = 256, NNEG = 16384;

// ---- workspace layout (float offsets) ---- total 5,309,440 floats (proven size)
// Squaring chain: P ping-pongs XA->XB->XA->XB->XA->XB (final A in XB, never overlaid).
// R ping-pongs T->S->T->S->T. NL overlays XA after; NH overlays T+S after.
constexpr size_t OFF_NL    = 0;         // 2M floats: neg-lo (overlays low region + XA)
constexpr size_t OFF_XA_H  = 1048576;
constexpr size_t OFF_XA_L  = 1572864;
constexpr size_t OFF_XB_H  = 2097152;   // FINAL A hi
constexpr size_t OFF_XB_L  = 2621440;
constexpr size_t OFF_NH    = 3145728;   // 2M floats: neg-hi (overlays T+S)
constexpr size_t OFF_T_H   = 3145728;
constexpr size_t OFF_CS    = 3145728;   // colsum[16][256] (inside T, consumed pre-Newton)
constexpr size_t OFF_C01   = 3149824;   // c0[16], c1[16]
constexpr size_t OFF_T_L   = 3670016;
constexpr size_t OFF_S_H   = 4194304;
constexpr size_t OFF_S_L   = 4718592;
constexpr size_t OFF_PA_H  = 5242880;   // 65536 ushorts
constexpr size_t OFF_PA_L  = 5275648;
constexpr size_t OFF_PAP   = 5308416;
constexpr size_t OFF_DPOS2 = 5308672;
constexpr size_t OFF_MINA  = 5308928;
constexpr size_t OFF_MINV  = 5309184;

// ---------- bf16 split helpers (RNE) ----------
__device__ inline unsigned short bf_hi(float x) {
    unsigned u = __float_as_uint(x);
    return (unsigned short)((u + 0x7fffu + ((u >> 16) & 1u)) >> 16);
}
__device__ inline float bf_tof(unsigned short h) { return __uint_as_float(((unsigned)h) << 16); }
__device__ inline void split2(float x, unsigned short& h, unsigned short& l) {
    h = bf_hi(x); l = bf_hi(x - bf_tof(h));
}

// ---------- prep 1: column abs-sums (Gershgorin), 256 blocks ----------
__global__ __launch_bounds__(256) void kcolsum(const float* __restrict__ Sig, float* __restrict__ cs) {
    int b = blockIdx.x >> 4, cg = blockIdx.x & 15;
    int t = threadIdx.x, tx = t & 15, rg = t >> 4;
    const float* S = Sig + (size_t)b * 65536;
    int col = cg * 16 + tx;
    float s = 0.f;
    #pragma unroll 4
    for (int i = rg * 16; i < rg * 16 + 16; ++i) s += fabsf(S[(size_t)i * 256 + col]);
    __shared__ float red[256];
    red[rg * 16 + tx] = s; __syncthreads();
    if (rg == 0) {
        float tot = 0.f;
        #pragma unroll
        for (int y = 0; y < 16; ++y) tot += red[y * 16 + tx];
        cs[b * 256 + col] = tot;
    }
}

// ---------- prep 2: G = max colsum -> degree-2 init coefficients ----------
__global__ __launch_bounds__(256) void kcoef(const float* __restrict__ cs, float* __restrict__ c01) {
    int t = threadIdx.x, b = t >> 4, ch = t & 15;
    float m = 0.f;
    #pragma unroll
    for (int i = 0; i < 16; ++i) m = fmaxf(m, cs[b * 256 + ch * 16 + i]);
    __shared__ float red[256];
    red[t] = m; __syncthreads();
    if (ch == 0) {
        float G = red[b * 16];
        #pragma unroll
        for (int y = 1; y < 16; ++y) G = fmaxf(G, red[b * 16 + y]);
        float c1 = -2.f / (G + (G + 1.f) * (G + 1.f) * 0.25f);
        c01[b] = -c1 * (G + 1.f); c01[16 + b] = c1;
    }
}

// ---------- prep 3: split S; P0 = X0 = c0*I + c1*S -> XA (split) ----------
__global__ __launch_bounds__(256) void kinit(const float* __restrict__ Sig, float* __restrict__ ws,
                                             const float* __restrict__ c01) {
    int idx = blockIdx.x * 256 + threadIdx.x;
    int b = idx >> 16, rc = idx & 65535;
    int r = rc >> 8, c = rc & 255;
    float v = Sig[idx];
    unsigned short h, l;
    split2(v, h, l);
    ((unsigned short*)(ws + OFF_S_H))[idx] = h; ((unsigned short*)(ws + OFF_S_L))[idx] = l;
    float x0 = c01[16 + b] * v + ((r == c) ? c01[b] : 0.f);
    split2(x0, h, l);
    ((unsigned short*)(ws + OFF_XA_H))[idx] = h; ((unsigned short*)(ws + OFF_XA_L))[idx] = l;
}

// ---------- unified Newton-squaring matmul kernel ----------
// Blocks qq<128 (P-half): C = op(PA@PB): pmode==2 -> I - PA@PB; pmode==3 -> PA@PB + PA.
// Blocks qq>=128 (R-half): RO = R@R. 32x32 tiles, dual accumulators, XCD-local b.
__global__ __launch_bounds__(256) void kmm(const unsigned short* __restrict__ PAh,
                                           const unsigned short* __restrict__ PAl,
                                           const unsigned short* __restrict__ PBh,
                                           const unsigned short* __restrict__ PBl,
                                           unsigned short* __restrict__ POh,
                                           unsigned short* __restrict__ POl, int pmode,
                                           const unsigned short* __restrict__ Rh,
                                           const unsigned short* __restrict__ Rl,
                                           unsigned short* __restrict__ ROh,
                                           unsigned short* __restrict__ ROl) {
    int lin = blockIdx.x;
    int x = lin & 7, qq = lin >> 3;
    int isP = (qq < 128) ? 1 : 0;
    int q2 = isP ? qq : (qq - 128);
    int b = x * 2 + (q2 >> 6);
    int tile = q2 & 63;
    int i0 = (tile >> 3) * 32, j0 = (tile & 7) * 32;
    size_t base = (size_t)b * 65536;
    const unsigned short* Ah = isP ? PAh : Rh;
    const unsigned short* Al = isP ? PAl : Rl;
    const unsigned short* Bh = isP ? PBh : Rh;
    const unsigned short* Bl = isP ? PBl : Rl;
    unsigned short* Ch = isP ? POh : ROh;
    unsigned short* Cl = isP ? POl : ROl;
    int t = threadIdx.x, lane = t & 63, w = t >> 6;
    int wi = w & 1, wj = w >> 1;
    int l15 = lane & 15, lg = lane >> 4;
    f32x4 acc0 = {}, acc1 = {};
    int ar = i0 + wi * 16 + l15;
    int br = j0 + wj * 16 + l15;
    #pragma unroll
    for (int e0 = 0; e0 < 256; e0 += 64) {
        int eo = e0 + 8 * lg;
        size_t aoff = base + (size_t)ar * 256 + eo;
        size_t boff = base + (size_t)br * 256 + eo;     // operands symmetric: row == col
        short8 a_h0 = *reinterpret_cast<const short8*>(Ah + aoff);
        short8 a_l0 = *reinterpret_cast<const short8*>(Al + aoff);
        short8 b_h0 = *reinterpret_cast<const short8*>(Bh + boff);
        short8 b_l0 = *reinterpret_cast<const short8*>(Bl + boff);
        short8 a_h1 = *reinterpret_cast<const short8*>(Ah + aoff + 32);
        short8 a_l1 = *reinterpret_cast<const short8*>(Al + aoff + 32);
        short8 b_h1 = *reinterpret_cast<const short8*>(Bh + boff + 32);
        short8 b_l1 = *reinterpret_cast<const short8*>(Bl + boff + 32);
        acc0 = __builtin_amdgcn_mfma_f32_16x16x32_bf16(a_h0, b_h0, acc0, 0, 0, 0);
        acc1 = __builtin_amdgcn_mfma_f32_16x16x32_bf16(a_h1, b_h1, acc1, 0, 0, 0);
        acc0 = __builtin_amdgcn_mfma_f32_16x16x32_bf16(a_h0, b_l0, acc0, 0, 0, 0);
        acc1 = __builtin_amdgcn_mfma_f32_16x16x32_bf16(a_h1, b_l1, acc1, 0, 0, 0);
        acc0 = __builtin_amdgcn_mfma_f32_16x16x32_bf16(a_l0, b_h0, acc0, 0, 0, 0);
        acc1 = __builtin_amdgcn_mfma_f32_16x16x32_bf16(a_l1, b_h1, acc1, 0, 0, 0);
    }
    #pragma unroll
    for (int r = 0; r < 4; ++r) {
        int row = i0 + wi * 16 + 4 * lg + r;
        int col = j0 + wj * 16 + l15;
        float v = acc0[r] + acc1[r];
        size_t off = base + (size_t)row * 256 + col;
        if (isP) {
            if (pmode == 2) v = ((row == col) ? 1.f : 0.f) - v;     // R0 = I - S@X0
            else            v += bf_tof(PAh[off]) + bf_tof(PAl[off]); // P' = P@R + P
        }
        unsigned short h, l; split2(v, h, l);
        Ch[off] = h; Cl[off] = l;
    }
}

// ---------- negatives pre-split (once) + min-buffer init ----------
__global__ __launch_bounds__(256) void knegsplit(const float* __restrict__ negs,
                                                 unsigned short* __restrict__ NH,
                                                 unsigned short* __restrict__ NL,
                                                 unsigned* __restrict__ mina,
                                                 unsigned* __restrict__ minv) {
    size_t i8 = ((size_t)blockIdx.x * 256 + threadIdx.x) * 8;
    f32x4 v0 = *reinterpret_cast<const f32x4*>(negs + i8);
    f32x4 v1 = *reinterpret_cast<const f32x4*>(negs + i8 + 4);
    short8 h, l;
    #pragma unroll
    for (int j = 0; j < 4; ++j) {
        unsigned short hh, ll;
        split2(v0[j], hh, ll); h[j] = (short)hh; l[j] = (short)ll;
        split2(v1[j], hh, ll); h[4 + j] = (short)hh; l[4 + j] = (short)ll;
    }
    *reinterpret_cast<short8*>(NH + i8) = h;
    *reinterpret_cast<short8*>(NL + i8) = l;
    if (blockIdx.x == 0) {
        mina[threadIdx.x] = 0x7f800000u; minv[threadIdx.x] = 0x7f800000u;
    }
}

// ---------- per (b,k): PA row (split), pAp, dpos2 ----------
__global__ __launch_bounds__(256) void k2(const float* __restrict__ Z1, const float* __restrict__ Z2,
                                          const int* __restrict__ match,
                                          const unsigned short* __restrict__ AH,
                                          const unsigned short* __restrict__ AL,
                                          float* __restrict__ ws) {
    int bk = blockIdx.x; int b = bk >> 4; int t = threadIdx.x;
    const unsigned short* Ah = AH + (size_t)b * 65536;
    const unsigned short* Al = AL + (size_t)b * 65536;
    __shared__ float z[DD], df[DD];
    __shared__ float red[256];
    int m = match[bk];
    float zv = Z1[(size_t)bk * DD + t];
    float qv = Z2[((size_t)b * KK + m) * DD + t];
    z[t] = zv; df[t] = zv - qv;
    __syncthreads();
    float pa = 0.f, da = 0.f;
    for (int e = 0; e < DD; ++e) {
        float Ae = bf_tof(Ah[(size_t)e * 256 + t]) + bf_tof(Al[(size_t)e * 256 + t]);
        pa = fmaf(z[e], Ae, pa);
        da = fmaf(df[e], Ae, da);
    }
    unsigned short ph, pl; split2(pa, ph, pl);
    ((unsigned short*)(ws + OFF_PA_H))[(size_t)bk * 256 + t] = ph;
    ((unsigned short*)(ws + OFF_PA_L))[(size_t)bk * 256 + t] = pl;
    float dfv = df[t];
    red[t] = pa * zv; __syncthreads();
    for (int s = 128; s > 0; s >>= 1) { if (t < s) red[t] += red[t + s]; __syncthreads(); }
    float pAp = red[0]; __syncthreads();
    red[t] = da * dfv; __syncthreads();
    for (int s = 128; s > 0; s >>= 1) { if (t < s) red[t] += red[t + s]; __syncthreads(); }
    if (t == 0) {
        ws[OFF_PAP + bk]   = pAp;
        ws[OFF_DPOS2 + bk] = fmaxf(red[0], EPS_);
    }
}

// ---------- main kernel: full-K XOR-swizzled LDS, zero-barrier loop, 2-deep a-prefetch ----------
// 512 thr = 8 waves. LDS: [64 rows][256 ushorts], 16B-block index ^= (row&7) (write+read).
// Wave w: f-tiles {2w, 2w+1}; PA j-split: wave w<4 does PA x (j=w).
__global__ __launch_bounds__(512, 2) void k3(const unsigned short* __restrict__ Ahi,
                                             const unsigned short* __restrict__ Alo,
                                             const unsigned short* __restrict__ PAh,
                                             const unsigned short* __restrict__ PAl,
                                             const unsigned short* __restrict__ NH,
                                             const unsigned short* __restrict__ NL,
                                             const float* __restrict__ pap,
                                             const float* __restrict__ dpos2,
                                             unsigned* __restrict__ mina,
                                             unsigned* __restrict__ minv) {
    __shared__ unsigned short Bh[64 * 256];            // 32 KB, swizzled
    __shared__ unsigned short Bl[64 * 256];            // 32 KB
    __shared__ float ep[2176];                         // 8.7 KB epilogue buffers

    int lin = blockIdx.x;
    int x  = lin & 7;
    int q  = lin >> 3;
    int b  = q >> 5;
    int n0 = (x * 32 + (q & 31)) * 64;                 // XCD-local 2048-n slice
    int t = threadIdx.x, lane = t & 63, w = t >> 6;
    int l15 = lane & 15, lg = lane >> 4;
    const unsigned short* Ab  = Ahi + (size_t)b * 65536;
    const unsigned short* Al_ = Alo + (size_t)b * 65536;
    const unsigned short* Nh  = NH + (size_t)n0 * 256;
    const unsigned short* Nl  = NL + (size_t)n0 * 256;

    // ---- one-shot swizzled staging: thread t -> row t>>3, 64B octant t&7 ----
    {
        int row = t >> 3, oct = t & 7, rsw = row & 7;
        const unsigned short* gh = Nh + (size_t)row * 256 + oct * 32;
        const unsigned short* gl = Nl + (size_t)row * 256 + oct * 32;
        #pragma unroll
        for (int k = 0; k < 4; ++k) {
            int sblk = (oct * 4 + k) ^ rsw;
            *reinterpret_cast<short8*>(Bh + row * 256 + sblk * 8) =
                *reinterpret_cast<const short8*>(gh + k * 8);
            *reinterpret_cast<short8*>(Bl + row * 256 + sblk * 8) =
                *reinterpret_cast<const short8*>(gl + k * 8);
        }
    }
    __syncthreads();                                   // the ONLY pre-compute barrier

    const unsigned short* aBh = Ab  + (size_t)(w * 32 + l15) * 256 + 8 * lg;  // f-tiles 2w,2w+1
    const unsigned short* aBl = Al_ + (size_t)(w * 32 + l15) * 256 + 8 * lg;
    const unsigned short* pph = PAh + (size_t)b * 4096 + (size_t)l15 * 256 + 8 * lg;
    const unsigned short* ppl = PAl + (size_t)b * 4096 + (size_t)l15 * 256 + 8 * lg;

    f32x4 acc0[4] = {}, acc1[4] = {};
    f32x4 accp = {};
    int rs0 = l15 & 7;                                 // read-row swizzle: (j*16+l15)&7

    // explicit 2-deep a-frag pipeline (static indices under full unroll)
    short8 a0h[2], a0l[2], a1h[2], a1l[2], qh8[2], ql8[2];
    a0h[0] = *reinterpret_cast<const short8*>(aBh);
    a0l[0] = *reinterpret_cast<const short8*>(aBl);
    a1h[0] = *reinterpret_cast<const short8*>(aBh + 16 * 256);
    a1l[0] = *reinterpret_cast<const short8*>(aBl + 16 * 256);
    if (w < 4) {
        qh8[0] = *reinterpret_cast<const short8*>(pph);
        ql8[0] = *reinterpret_cast<const short8*>(ppl);
    }

    #pragma unroll
    for (int c = 0; c < 8; ++c) {
        const int cur = c & 1, nxt = cur ^ 1;
        if (c < 7) {                                    // prefetch chunk c+1 (one chunk deep)
            a0h[nxt] = *reinterpret_cast<const short8*>(aBh + (c + 1) * 32);
            a0l[nxt] = *reinterpret_cast<const short8*>(aBl + (c + 1) * 32);
            a1h[nxt] = *reinterpret_cast<const short8*>(aBh + 16 * 256 + (c + 1) * 32);
            a1l[nxt] = *reinterpret_cast<const short8*>(aBl + 16 * 256 + (c + 1) * 32);
            if (w < 4) {
                qh8[nxt] = *reinterpret_cast<const short8*>(pph + (c + 1) * 32);
                ql8[nxt] = *reinterpret_cast<const short8*>(ppl + (c + 1) * 32);
            }
        }
        #pragma unroll
        for (int j = 0; j < 4; ++j) {
            int ro = (j * 16 + l15) * 256 + (((c * 4 + lg) ^ rs0) * 8);
            short8 bh = *reinterpret_cast<const short8*>(Bh + ro);
            short8 bl = *reinterpret_cast<const short8*>(Bl + ro);
            acc0[j] = __builtin_amdgcn_mfma_f32_16x16x32_bf16(a0h[cur], bh, acc0[j], 0, 0, 0);
            acc0[j] = __builtin_amdgcn_mfma_f32_16x16x32_bf16(a0h[cur], bl, acc0[j], 0, 0, 0);
            acc0[j] = __builtin_amdgcn_mfma_f32_16x16x32_bf16(a0l[cur], bh, acc0[j], 0, 0, 0);
            acc1[j] = __builtin_amdgcn_mfma_f32_16x16x32_bf16(a1h[cur], bh, acc1[j], 0, 0, 0);
            acc1[j] = __builtin_amdgcn_mfma_f32_16x16x32_bf16(a1h[cur], bl, acc1[j], 0, 0, 0);
            acc1[j] = __builtin_amdgcn_mfma_f32_16x16x32_bf16(a1l[cur], bh, acc1[j], 0, 0, 0);
            if (w == j) {                               // w<4 implied
                accp = __builtin_amdgcn_mfma_f32_16x16x32_bf16(qh8[cur], bh, accp, 0, 0, 0);
                accp = __builtin_amdgcn_mfma_f32_16x16x32_bf16(qh8[cur], bl, accp, 0, 0, 0);
                accp = __builtin_amdgcn_mfma_f32_16x16x32_bf16(ql8[cur], bh, accp, 0, 0, 0);
            }
        }
    }

    // ---- epilogue: weights from swizzled LDS; cross-wave reduce in ep[] ----
    float* pAn_l = ep;              // [64][17] = 1088
    float* nAnp  = ep + 1088;       // [8][64]
    float* nAn_l = ep + 1600;       // [64]
    float* reda  = ep + 1664;       // [256]
    float* redv  = ep + 1920;       // [256]

    if (w < 4) {                                        // pAn for n = w*16+l15, k = 4lg+r
        #pragma unroll
        for (int r = 0; r < 4; ++r)
            pAn_l[(w * 16 + l15) * 17 + 4 * lg + r] = accp[r];
    }
    int bb = w * 4 + (lg >> 1);
    int sub = (lg & 1) * 4;
    #pragma unroll
    for (int j = 0; j < 4; ++j) {
        int n = j * 16 + l15;
        float p = 0.f;
        {
            ushort4v wh0 = *reinterpret_cast<const ushort4v*>(Bh + n * 256 + ((bb    ) ^ rs0) * 8 + sub);
            ushort4v wl0 = *reinterpret_cast<const ushort4v*>(Bl + n * 256 + ((bb    ) ^ rs0) * 8 + sub);
            ushort4v wh1 = *reinterpret_cast<const ushort4v*>(Bh + n * 256 + ((bb + 2) ^ rs0) * 8 + sub);
            ushort4v wl1 = *reinterpret_cast<const ushort4v*>(Bl + n * 256 + ((bb + 2) ^ rs0) * 8 + sub);
            #pragma unroll
            for (int r = 0; r < 4; ++r) {
                p = fmaf(acc0[j][r], bf_tof(wh0[r]) + bf_tof(wl0[r]), p);
                p = fmaf(acc1[j][r], bf_tof(wh1[r]) + bf_tof(wl1[r]), p);
            }
        }
        p += __shfl_xor(p, 16);                         // reduce over lg
        p += __shfl_xor(p, 32);
        if (lane < 16) nAnp[w * 64 + n] = p;
    }
    __syncthreads();
    if (t < 64) {
        float s = 0.f;
        #pragma unroll
        for (int ww = 0; ww < 8; ++ww) s += nAnp[ww * 64 + t];
        nAn_l[t] = s;
    }
    __syncthreads();
    if (t < 256) {
        int tx = t & 15, ty = t >> 4;                   // ty 0..15, 4 n each
        float pApk = pap[b * 16 + tx];
        float dp2  = dpos2[b * 16 + tx];
        float mn_a = __uint_as_float(0x7f800000u), mn_v = mn_a;
        #pragma unroll
        for (int ii = 0; ii < 4; ++ii) {
            int n = ty * 4 + ii;
            float d2v = pApk - 2.f * pAn_l[n * 17 + tx] + nAn_l[n];
            float cc = fmaxf(d2v, EPS_);
            mn_a = fminf(mn_a, cc);
            if (cc > dp2) mn_v = fminf(mn_v, cc);
        }
        reda[ty * 16 + tx] = mn_a; redv[ty * 16 + tx] = mn_v;
    }
    __syncthreads();
    if (t < 16) {
        float ra = reda[t], rv = redv[t];
        #pragma unroll
        for (int y = 1; y < 16; ++y) {
            ra = fminf(ra, reda[y * 16 + t]);
            rv = fminf(rv, redv[y * 16 + t]);
        }
        atomicMin(&mina[b * 16 + t], __float_as_uint(ra));
        atomicMin(&minv[b * 16 + t], __float_as_uint(rv));
    }
}

// ---------- final loss ----------
__global__ __launch_bounds__(256) void k5(const float* __restrict__ dpos2,
                                          const unsigned* __restrict__ mina,
                                          const unsigned* __restrict__ minv,
                                          float* __restrict__ out) {
    int t = threadIdx.x;
    __shared__ float red[256];
    float dp = sqrtf(dpos2[t]);
    unsigned mv = minv[t], ma = mina[t];
    unsigned sel = (mv < 0x7f800000u) ? mv : ma;
    float dn = sqrtf(__uint_as_float(sel));
    red[t] = fmaxf(dp - dn + ALPHA_, 0.f);
    __syncthreads();
    for (int s = 128; s > 0; s >>= 1) { if (t < s) red[t] += red[t + s]; __syncthreads(); }
    if (t == 0) out[0] = red[0] * (1.f / 256.f);
}

extern "C" void kernel_launch(void* const* d_in, const int* in_sizes, int n_in,
                              void* d_out, int out_size, void* d_ws, size_t ws_size,
                              hipStream_t stream) {
    (void)in_sizes; (void)n_in; (void)out_size; (void)ws_size;
    const float* Z1   = (const float*)d_in[0];
    const float* Z2   = (const float*)d_in[1];
    const int*   mat  = (const int*)d_in[2];
    const float* negs = (const float*)d_in[3];
    const float* Sig  = (const float*)d_in[4];
    float* ws = (float*)d_ws;
    unsigned short* S_H  = (unsigned short*)(ws + OFF_S_H);
    unsigned short* S_L  = (unsigned short*)(ws + OFF_S_L);
    unsigned short* XA_H = (unsigned short*)(ws + OFF_XA_H);
    unsigned short* XA_L = (unsigned short*)(ws + OFF_XA_L);
    unsigned short* XB_H = (unsigned short*)(ws + OFF_XB_H);
    unsigned short* XB_L = (unsigned short*)(ws + OFF_XB_L);
    unsigned short* T_H  = (unsigned short*)(ws + OFF_T_H);
    unsigned short* T_L  = (unsigned short*)(ws + OFF_T_L);
    unsigned short* PA_H = (unsigned short*)(ws + OFF_PA_H);
    unsigned short* PA_L = (unsigned short*)(ws + OFF_PA_L);
    unsigned short* NH   = (unsigned short*)(ws + OFF_NH);
    unsigned short* NL   = (unsigned short*)(ws + OFF_NL);
    unsigned* mina = (unsigned*)(ws + OFF_MINA);
    unsigned* minv = (unsigned*)(ws + OFF_MINV);
    float* out = (float*)d_out;

    kcolsum<<<256, 256, 0, stream>>>(Sig, ws + OFF_CS);
    kcoef<<<1, 256, 0, stream>>>(ws + OFF_CS, ws + OFF_C01);
    kinit<<<4096, 256, 0, stream>>>(Sig, ws, ws + OFF_C01);   // P0 = X0 -> XA

    // R0 = I - S@P0 -> T   (1024 blocks: P-half only, pmode=2)
    kmm<<<1024, 256, 0, stream>>>(S_H, S_L, XA_H, XA_L, T_H, T_L, 2, S_H, S_L, T_H, T_L);
    // stage 0: P1 = P0 + P0@R0 -> XB; R1 = R0^2 -> S
    kmm<<<2048, 256, 0, stream>>>(XA_H, XA_L, T_H, T_L, XB_H, XB_L, 3, T_H, T_L, S_H, S_L);
    // stage 1: P2 -> XA; R2 -> T
    kmm<<<2048, 256, 0, stream>>>(XB_H, XB_L, S_H, S_L, XA_H, XA_L, 3, S_H, S_L, T_H, T_L);
    // stage 2: P3 -> XB; R3 -> S
    kmm<<<2048, 256, 0, stream>>>(XA_H, XA_L, T_H, T_L, XB_H, XB_L, 3, T_H, T_L, S_H, S_L);
    // stage 3: P4 -> XA; R4 -> T
    kmm<<<2048, 256, 0, stream>>>(XB_H, XB_L, S_H, S_L, XA_H, XA_L, 3, S_H, S_L, T_H, T_L);
    // stage 4: P5 = final A -> XB (no R-half)
    kmm<<<1024, 256, 0, stream>>>(XA_H, XA_L, T_H, T_L, XB_H, XB_L, 3, S_H, S_L, T_H, T_L);
    // residual = R0^32 ~ rho0^32 ~ 1e-5 (same as 5 Newton iterations; proven config)

    knegsplit<<<NNEG * DD / 8 / 256, 256, 0, stream>>>(negs, NH, NL, mina, minv);
    k2<<<BB * KK, 256, 0, stream>>>(Z1, Z2, mat, XB_H, XB_L, ws);
    k3<<<BB * NNEG / 64, 512, 0, stream>>>(XB_H, XB_L, PA_H, PA_L, NH, NL,
                                           ws + OFF_PAP, ws + OFF_DPOS2, mina, minv);
    k5<<<1, 256, 0, stream>>>(ws + OFF_DPOS2, mina, minv, out);
}